// Round 4
// baseline (206.556 us; speedup 1.0000x reference)
//
#include <hip/hip_runtime.h>
#include <math.h>

#define N 8192
#define D 512
#define NEG_INF_SENT (-3.0e38f)

typedef __attribute__((ext_vector_type(8))) short short8x;   // 8 bf16 in 4 VGPRs
typedef __attribute__((ext_vector_type(4))) float f32x4;

__device__ inline void lse_merge(float& m1, float& s1, float m2, float s2) {
    float M = fmaxf(m1, m2);
    s1 = s1 * __expf(m1 - M) + s2 * __expf(m2 - M);
    m1 = M;
}

__device__ inline unsigned short bf16_rne(float f) {
    union { float f; unsigned u; } c; c.f = f;
    unsigned u = c.u;
    return (unsigned short)((u + 0x7FFFu + ((u >> 16) & 1u)) >> 16);
}

// ---- fused cast + row-sumsq: one wave per row --------------------------------
__global__ __launch_bounds__(256) void cast_rowsq_kernel(const float* __restrict__ x,
                                                         short* __restrict__ xb,
                                                         float* __restrict__ sq) {
    int row = blockIdx.x * 4 + (threadIdx.x >> 6);
    int lane = threadIdx.x & 63;
    const float4* xr = (const float4*)(x + (size_t)row * D);
    float4 a = xr[lane * 2], b = xr[lane * 2 + 1];
    float v[8] = {a.x, a.y, a.z, a.w, b.x, b.y, b.z, b.w};
    float s = 0.f;
    unsigned short h[8];
#pragma unroll
    for (int e = 0; e < 8; ++e) { s += v[e] * v[e]; h[e] = bf16_rne(v[e]); }
    uint4 pk;
    pk.x = (unsigned)h[0] | ((unsigned)h[1] << 16);
    pk.y = (unsigned)h[2] | ((unsigned)h[3] << 16);
    pk.z = (unsigned)h[4] | ((unsigned)h[5] << 16);
    pk.w = (unsigned)h[6] | ((unsigned)h[7] << 16);
    ((uint4*)xb)[(size_t)row * 64 + lane] = pk;
#pragma unroll
    for (int off = 32; off > 0; off >>= 1) s += __shfl_down(s, off, 64);
    if (lane == 0) sq[row] = s;
}

// ---- LDS-free MFMA pair kernel: fragments loaded straight from global --------
// 128x128 block tile, 4 waves, each wave 64x64 via 4x4 frags of 16x16x32 bf16.
// No __syncthreads in the K-loop: register double-buffer, loads fully
// coalesced (per fragment load, 4 kq-lanes consume one 64B line; 16 lines
// per instruction, 100% utilized). Fragment layout identical to the verified
// round-3 staging (A[m=lane&15][k=(lane>>4)*8+j]).
__global__ __launch_bounds__(256) void pair_mfma_kernel(const short* __restrict__ xb,
                                                        const float* __restrict__ sq,
                                                        float* __restrict__ bm,
                                                        float* __restrict__ bs) {
    const int T = N / 128;  // 64
    const int b = blockIdx.x;
    int bi = (int)((2 * T + 1 - sqrtf((float)((2 * T + 1) * (2 * T + 1) - 8 * b))) * 0.5f);
    if (bi < 0) bi = 0;
    if (bi > T - 1) bi = T - 1;
    while ((bi + 1) * (2 * T - bi) / 2 <= b) ++bi;
    while (bi * (2 * T - bi + 1) / 2 > b) --bi;
    const int bj = bi + (b - bi * (2 * T - bi + 1) / 2);
    const int i0 = bi * 128, j0 = bj * 128;

    const int tid = threadIdx.x;
    const int lane = tid & 63;
    const int w = tid >> 6;          // wave 0..3
    const int wy = w >> 1, wx = w & 1;
    const int frow = lane & 15;
    const int kq = lane >> 4;

    const short* ap[4];
    const short* bp[4];
#pragma unroll
    for (int t = 0; t < 4; ++t) {
        ap[t] = xb + (size_t)(i0 + wy * 64 + t * 16 + frow) * D + kq * 8;
        bp[t] = xb + (size_t)(j0 + wx * 64 + t * 16 + frow) * D + kq * 8;
    }

    f32x4 acc[4][4];
#pragma unroll
    for (int mi = 0; mi < 4; ++mi)
#pragma unroll
        for (int ni = 0; ni < 4; ++ni) acc[mi][ni] = (f32x4){0.f, 0.f, 0.f, 0.f};

    short8x af[2][4], bf[2][4];
#pragma unroll
    for (int t = 0; t < 4; ++t) {
        af[0][t] = *(const short8x*)(ap[t]);
        bf[0][t] = *(const short8x*)(bp[t]);
    }

#pragma unroll
    for (int s = 0; s < 16; ++s) {            // 16 K-steps of 32
        const int cur = s & 1, nxt = cur ^ 1;
        if (s < 15) {
            const int koff = (s + 1) * 32;
#pragma unroll
            for (int t = 0; t < 4; ++t) {
                af[nxt][t] = *(const short8x*)(ap[t] + koff);
                bf[nxt][t] = *(const short8x*)(bp[t] + koff);
            }
        }
#pragma unroll
        for (int mi = 0; mi < 4; ++mi)
#pragma unroll
            for (int ni = 0; ni < 4; ++ni)
                acc[mi][ni] = __builtin_amdgcn_mfma_f32_16x16x32_bf16(
                    af[cur][mi], bf[cur][ni], acc[mi][ni], 0, 0, 0);
    }

    // ---- branch-free epilogue: t = -2*d2 into acc regs, max-pass, exp-pass ---
    const int rbase = kq * 4;     // C/D: row=(lane>>4)*4+reg, col=lane&15
    const bool offdiag = (bi != bj);
    float sqj[4];
#pragma unroll
    for (int ni = 0; ni < 4; ++ni) sqj[ni] = sq[j0 + wx * 64 + ni * 16 + frow];

    float m = NEG_INF_SENT;
#pragma unroll
    for (int mi = 0; mi < 4; ++mi) {
#pragma unroll
        for (int r = 0; r < 4; ++r) {
            int i = i0 + wy * 64 + mi * 16 + rbase + r;
            float sqi = sq[i];
#pragma unroll
            for (int ni = 0; ni < 4; ++ni) {
                int j = j0 + wx * 64 + ni * 16 + frow;
                float d2 = fmaxf(sqi + sqj[ni] - 2.f * acc[mi][ni][r], 0.f);
                float tv = (offdiag || j > i) ? (-2.0f * d2) : NEG_INF_SENT;
                acc[mi][ni][r] = tv;
                m = fmaxf(m, tv);
            }
        }
    }
    float s = 0.f;
#pragma unroll
    for (int mi = 0; mi < 4; ++mi)
#pragma unroll
        for (int ni = 0; ni < 4; ++ni)
#pragma unroll
            for (int r = 0; r < 4; ++r)
                s += __expf(acc[mi][ni][r] - m);
    // all-invalid lanes: m = sentinel, s = 64 -> zeroed by exp(m-M) in merge

#pragma unroll
    for (int off = 32; off > 0; off >>= 1) {
        float m2 = __shfl_down(m, off, 64);
        float s2 = __shfl_down(s, off, 64);
        lse_merge(m, s, m2, s2);
    }
    __shared__ float rm[4], rs[4];
    if (lane == 0) { rm[w] = m; rs[w] = s; }
    __syncthreads();
    if (tid == 0) {
#pragma unroll
        for (int v = 1; v < 4; ++v) lse_merge(rm[0], rs[0], rm[v], rs[v]);
        bm[b] = rm[0];
        bs[b] = rs[0];
    }
}

__global__ __launch_bounds__(256) void finalize_kernel(const float* __restrict__ bm,
                                                       const float* __restrict__ bs,
                                                       int nblocks,
                                                       float* __restrict__ out) {
    const int tid = threadIdx.x;
    float m = NEG_INF_SENT, s = 0.f;
    for (int b = tid; b < nblocks; b += 256) lse_merge(m, s, bm[b], bs[b]);
#pragma unroll
    for (int off = 32; off > 0; off >>= 1) {
        float m2 = __shfl_down(m, off, 64);
        float s2 = __shfl_down(s, off, 64);
        lse_merge(m, s, m2, s2);
    }
    __shared__ float rm[4], rs[4];
    if ((tid & 63) == 0) { rm[tid >> 6] = m; rs[tid >> 6] = s; }
    __syncthreads();
    if (tid == 0) {
#pragma unroll
        for (int v = 1; v < 4; ++v) lse_merge(rm[0], rs[0], rm[v], rs[v]);
        const float log_num_pairs = 17.3285362f;  // log(8192*8191/2)
        out[0] = rm[0] + logf(rs[0]) - log_num_pairs;
    }
}

extern "C" void kernel_launch(void* const* d_in, const int* in_sizes, int n_in,
                              void* d_out, int out_size, void* d_ws, size_t ws_size,
                              hipStream_t stream) {
    const float* x = (const float*)d_in[0];
    float* out = (float*)d_out;

    const int Tm = N / 128;
    const int nb = Tm * (Tm + 1) / 2;                 // 2080
    const size_t xb_bytes = (size_t)N * D * sizeof(short);  // 8 MB

    short* xb = (short*)d_ws;
    float* sq = (float*)((char*)d_ws + xb_bytes);
    float* bm = sq + N;
    float* bs = bm + nb;

    cast_rowsq_kernel<<<N / 4, 256, 0, stream>>>(x, xb, sq);
    pair_mfma_kernel<<<nb, 256, 0, stream>>>(xb, sq, bm, bs);
    finalize_kernel<<<1, 256, 0, stream>>>(bm, bs, nb, out);
}

// Round 5
// 135.752 us; speedup vs baseline: 1.5216x; 1.5216x over previous
//
#include <hip/hip_runtime.h>
#include <math.h>

#define N 8192
#define D 512
#define NEG_INF_SENT (-3.0e38f)

typedef __attribute__((ext_vector_type(8))) short short8x;   // 8 bf16 in 4 VGPRs
typedef __attribute__((ext_vector_type(4))) float f32x4;

#define AS1 __attribute__((address_space(1)))
#define AS3 __attribute__((address_space(3)))

__device__ inline void lse_merge(float& m1, float& s1, float m2, float s2) {
    float M = fmaxf(m1, m2);
    s1 = s1 * __expf(m1 - M) + s2 * __expf(m2 - M);
    m1 = M;
}

__device__ inline unsigned short bf16_rne(float f) {
    union { float f; unsigned u; } c; c.f = f;
    unsigned u = c.u;
    return (unsigned short)((u + 0x7FFFu + ((u >> 16) & 1u)) >> 16);
}

// ---- fused cast + row-sumsq: one wave per row, 16 rows per block -------------
__global__ __launch_bounds__(256) void cast_rowsq_kernel(const float* __restrict__ x,
                                                         short* __restrict__ xb,
                                                         float* __restrict__ sq) {
#pragma unroll
    for (int g = 0; g < 4; ++g) {
        int row = blockIdx.x * 16 + g * 4 + (threadIdx.x >> 6);
        int lane = threadIdx.x & 63;
        const float4* xr = (const float4*)(x + (size_t)row * D);
        float4 a = xr[lane * 2], b = xr[lane * 2 + 1];
        float v[8] = {a.x, a.y, a.z, a.w, b.x, b.y, b.z, b.w};
        float s = 0.f;
        unsigned short h[8];
#pragma unroll
        for (int e = 0; e < 8; ++e) { s += v[e] * v[e]; h[e] = bf16_rne(v[e]); }
        uint4 pk;
        pk.x = (unsigned)h[0] | ((unsigned)h[1] << 16);
        pk.y = (unsigned)h[2] | ((unsigned)h[3] << 16);
        pk.z = (unsigned)h[4] | ((unsigned)h[5] << 16);
        pk.w = (unsigned)h[6] | ((unsigned)h[7] << 16);
        ((uint4*)xb)[(size_t)row * 64 + lane] = pk;
#pragma unroll
        for (int off = 32; off > 0; off >>= 1) s += __shfl_down(s, off, 64);
        if (lane == 0) sq[row] = s;
    }
}

// ---- MFMA pair kernel: 256x256 tile, 8 waves, dbuf LDS, XCD-swizzled ---------
// Wave-tile 64(i) x 128(j): acc[4][8] frags of 16x16x32 bf16.
// LDS fragment-order (verified r3): frag f = 16 rows x 32 k, lane l holds
// row (l&15), k-quad (l>>4): one 16B DMA per lane, read back at lane*16.
__global__ __launch_bounds__(512, 2) void pair_mfma_kernel(const short* __restrict__ xb,
                                                           const float* __restrict__ sq,
                                                           float* __restrict__ bm,
                                                           float* __restrict__ bs) {
    __shared__ __align__(16) short A_lds[2][16][2][512];   // 64 KB
    __shared__ __align__(16) short B_lds[2][16][2][512];   // 64 KB

    const int T = N / 256;  // 32
    // XCD-aware swizzle: 528 = 8*66; give each XCD a contiguous triangle run
    const int b = (blockIdx.x & 7) * 66 + (blockIdx.x >> 3);
    int bi = (int)((2 * T + 1 - sqrtf((float)((2 * T + 1) * (2 * T + 1) - 8 * b))) * 0.5f);
    if (bi < 0) bi = 0;
    if (bi > T - 1) bi = T - 1;
    while ((bi + 1) * (2 * T - bi) / 2 <= b) ++bi;
    while (bi * (2 * T - bi + 1) / 2 > b) --bi;
    const int bj = bi + (b - bi * (2 * T - bi + 1) / 2);
    const int i0 = bi * 256, j0 = bj * 256;

    const int tid = threadIdx.x;
    const int lane = tid & 63;
    const int w = tid >> 6;          // wave 0..7
    const int wy = w >> 1;           // 0..3  (i 64-chunk)
    const int wx = w & 1;            // 0..1  (j 128-chunk)
    const int frow = lane & 15;
    const int kq = lane >> 4;

    // stage one K-chunk (64 k) into buffer `buf`: 64 frags, 8 per wave
    auto stage = [&](int k0, int buf) {
#pragma unroll
        for (int q = 0; q < 8; ++q) {
            int f = (w << 3) | q;            // 0..63, wave-uniform
            int isA = (f < 32);
            int fr = (f & 31) >> 1;          // frag-row 0..15
            int ks = f & 1;
            int grow = (isA ? i0 : j0) + fr * 16 + frow;
            const short* g = xb + (size_t)grow * D + k0 + ks * 32 + kq * 8;
            short* l = isA ? &A_lds[buf][fr][ks][0] : &B_lds[buf][fr][ks][0];
            __builtin_amdgcn_global_load_lds((const AS1 void*)g, (AS3 void*)l, 16, 0, 0);
        }
    };

    f32x4 acc[4][8];
#pragma unroll
    for (int mi = 0; mi < 4; ++mi)
#pragma unroll
        for (int ni = 0; ni < 8; ++ni) acc[mi][ni] = (f32x4){0.f, 0.f, 0.f, 0.f};

    stage(0, 0);
    __syncthreads();

    for (int s = 0; s < 8; ++s) {
        const int cur = s & 1;
        if (s < 7) stage((s + 1) * 64, cur ^ 1);
#pragma unroll
        for (int ks = 0; ks < 2; ++ks) {
            short8x a_frag[4], b_frag[8];
#pragma unroll
            for (int t = 0; t < 4; ++t)
                a_frag[t] = *(const short8x*)&A_lds[cur][wy * 4 + t][ks][lane << 3];
#pragma unroll
            for (int u = 0; u < 8; ++u)
                b_frag[u] = *(const short8x*)&B_lds[cur][wx * 8 + u][ks][lane << 3];
#pragma unroll
            for (int mi = 0; mi < 4; ++mi)
#pragma unroll
                for (int ni = 0; ni < 8; ++ni)
                    acc[mi][ni] = __builtin_amdgcn_mfma_f32_16x16x32_bf16(
                        a_frag[mi], b_frag[ni], acc[mi][ni], 0, 0, 0);
        }
        __syncthreads();   // drains vmcnt (stage s+1) + lgkm; covered by the 64 MFMA above
    }

    // ---- branch-free epilogue: t = -2*d2, max-pass, exp-pass -----------------
    const int rbase = kq * 4;        // C/D: row=(lane>>4)*4+reg, col=lane&15
    const bool offdiag = (bi != bj);
    float sqj[8];
#pragma unroll
    for (int ni = 0; ni < 8; ++ni) sqj[ni] = sq[j0 + wx * 128 + ni * 16 + frow];

    float m = NEG_INF_SENT;
#pragma unroll
    for (int mi = 0; mi < 4; ++mi) {
#pragma unroll
        for (int r = 0; r < 4; ++r) {
            int i = i0 + wy * 64 + mi * 16 + rbase + r;
            float sqi = sq[i];
#pragma unroll
            for (int ni = 0; ni < 8; ++ni) {
                int j = j0 + wx * 128 + ni * 16 + frow;
                float d2 = fmaxf(sqi + sqj[ni] - 2.f * acc[mi][ni][r], 0.f);
                float tv = (offdiag || j > i) ? (-2.0f * d2) : NEG_INF_SENT;
                acc[mi][ni][r] = tv;
                m = fmaxf(m, tv);
            }
        }
    }
    float s = 0.f;
#pragma unroll
    for (int mi = 0; mi < 4; ++mi)
#pragma unroll
        for (int ni = 0; ni < 8; ++ni)
#pragma unroll
            for (int r = 0; r < 4; ++r)
                s += __expf(acc[mi][ni][r] - m);

#pragma unroll
    for (int off = 32; off > 0; off >>= 1) {
        float m2 = __shfl_down(m, off, 64);
        float s2 = __shfl_down(s, off, 64);
        lse_merge(m, s, m2, s2);
    }
    __shared__ float rm[8], rs[8];
    if (lane == 0) { rm[w] = m; rs[w] = s; }
    __syncthreads();
    if (tid == 0) {
#pragma unroll
        for (int v = 1; v < 8; ++v) lse_merge(rm[0], rs[0], rm[v], rs[v]);
        bm[b] = rm[0];
        bs[b] = rs[0];
    }
}

__global__ __launch_bounds__(256) void finalize_kernel(const float* __restrict__ bm,
                                                       const float* __restrict__ bs,
                                                       int nblocks,
                                                       float* __restrict__ out) {
    const int tid = threadIdx.x;
    float m = NEG_INF_SENT, s = 0.f;
    for (int b = tid; b < nblocks; b += 256) lse_merge(m, s, bm[b], bs[b]);
#pragma unroll
    for (int off = 32; off > 0; off >>= 1) {
        float m2 = __shfl_down(m, off, 64);
        float s2 = __shfl_down(s, off, 64);
        lse_merge(m, s, m2, s2);
    }
    __shared__ float rm[4], rs[4];
    if ((tid & 63) == 0) { rm[tid >> 6] = m; rs[tid >> 6] = s; }
    __syncthreads();
    if (tid == 0) {
#pragma unroll
        for (int v = 1; v < 4; ++v) lse_merge(rm[0], rs[0], rm[v], rs[v]);
        const float log_num_pairs = 17.3285362f;  // log(8192*8191/2)
        out[0] = rm[0] + logf(rs[0]) - log_num_pairs;
    }
}

extern "C" void kernel_launch(void* const* d_in, const int* in_sizes, int n_in,
                              void* d_out, int out_size, void* d_ws, size_t ws_size,
                              hipStream_t stream) {
    const float* x = (const float*)d_in[0];
    float* out = (float*)d_out;

    const int T = N / 256;                    // 32
    const int nb = T * (T + 1) / 2;           // 528
    const size_t xb_bytes = (size_t)N * D * sizeof(short);  // 8 MB

    short* xb = (short*)d_ws;
    float* sq = (float*)((char*)d_ws + xb_bytes);
    float* bm = sq + N;
    float* bs = bm + nb;

    cast_rowsq_kernel<<<N / 16, 256, 0, stream>>>(x, xb, sq);
    pair_mfma_kernel<<<nb, 512, 0, stream>>>(xb, sq, bm, bs);
    finalize_kernel<<<1, 256, 0, stream>>>(bm, bs, nb, out);
}